// Round 5
// baseline (166.954 us; speedup 1.0000x reference)
//
#include <hip/hip_runtime.h>
#include <math.h>

#define N_ 8192
#define D_ 512
#define NC_ 128
#define T_ 64   // 8192/128 row-tiles

typedef __attribute__((ext_vector_type(8))) short bf16x8;
typedef __attribute__((ext_vector_type(4))) float f32x4;
typedef __attribute__((ext_vector_type(4))) unsigned short us4;

static __device__ __forceinline__ unsigned short f2bf(float f) {
    union { float f; unsigned u; } c; c.f = f;
    unsigned u = c.u;
    u += 0x7fffu + ((u >> 16) & 1u);   // round-to-nearest-even
    return (unsigned short)(u >> 16);
}

// ---------- kernel 1: fp32 -> bf16 ----------
__global__ __launch_bounds__(256) void k_convert(const float* __restrict__ x,
                                                 unsigned short* __restrict__ xb) {
    int i = (blockIdx.x * 256 + threadIdx.x);
    float4 v = reinterpret_cast<const float4*>(x)[i];
    us4 o = { f2bf(v.x), f2bf(v.y), f2bf(v.z), f2bf(v.w) };
    reinterpret_cast<us4*>(xb)[i] = o;
}

// ---------- kernel 2: symmetric fused MFMA sim + masked exp partials ----------
// 512 threads (8 waves, 2 wrow x 4 wcol), 128x256 tile = two 128x128 subtiles.
// Block (it, jt2): rows [128it,128it+128), cols [256jt2,256jt2+256).
// Subtile b in {2jt2, 2jt2+1}: b<it dead (zero contribution), b==it row-only,
// b>it row+col. Partials -> packed slots in buf[t][s][128], no atomics:
//   col-sourced (tile t=b, writer a=it): s = a            (a < t)
//   row-sourced (tile t=it, writer jt2): s = t + jt2 - (t>>1)
__global__ __launch_bounds__(512, 4) void k_main(const unsigned short* __restrict__ xb,
                                                 const int* __restrict__ tg,
                                                 float* __restrict__ bufP,
                                                 float* __restrict__ bufN) {
    __shared__ alignas(16) unsigned short As[128 * 64];   // 16 KB
    __shared__ alignas(16) unsigned short Bs[256 * 64];   // 32 KB
    __shared__ int rowT[128];

    const int tid  = threadIdx.x;
    const int w    = tid >> 6;       // 0..7
    const int lane = tid & 63;
    const int q    = lane >> 4;
    const int l15  = lane & 15;
    const int wrow = w >> 2;         // 0..1
    const int wcol = w & 3;          // 0..3

    // decode blockIdx.x -> (it, jt2): jt2 in [it>>1, 32)
    int rem = blockIdx.x;
    int it = 0;
    while (rem >= 32 - (it >> 1)) { rem -= 32 - (it >> 1); it++; }
    const int jt2  = (it >> 1) + rem;
    const int row0 = it * 128;
    const int col0 = jt2 * 256;

    const int bsub   = 2 * jt2 + (wcol >> 1);   // this wave's 128-col subtile
    const bool rowOK = (bsub >= it);
    // col contributions gated at store by (bc > it)

    if (tid < 128) rowT[tid] = tg[row0 + tid];
    __syncthreads();

    int tR[4][4];
#pragma unroll
    for (int mi = 0; mi < 4; ++mi)
#pragma unroll
        for (int r = 0; r < 4; ++r)
            tR[mi][r] = rowT[wrow * 64 + mi * 16 + q * 4 + r];

    int tC[4];
#pragma unroll
    for (int ni = 0; ni < 4; ++ni)
        tC[ni] = tg[col0 + wcol * 64 + ni * 16 + l15];

    f32x4 acc[4][4];
#pragma unroll
    for (int mi = 0; mi < 4; ++mi)
#pragma unroll
        for (int ni = 0; ni < 4; ++ni)
            acc[mi][ni] = (f32x4){0.f, 0.f, 0.f, 0.f};

    for (int ks = 0; ks < 8; ++ks) {
        const int k0 = ks * 64;
        __syncthreads();   // prior ds_reads done before restaging
        // A: 1024 slots of 16B (2 issues), B: 2048 slots (4 issues);
        // XOR swizzle: LDS slot s holds kgroup g = s ^ (row&7)
#pragma unroll
        for (int i2 = 0; i2 < 2; ++i2) {
            int slot = i2 * 512 + tid;
            int r  = slot >> 3;
            int s  = slot & 7;
            int g  = s ^ (r & 7);
            const unsigned short* ga = xb + (size_t)(row0 + r) * D_ + k0 + g * 8;
            __builtin_amdgcn_global_load_lds(
                (const __attribute__((address_space(1))) void*)ga,
                (__attribute__((address_space(3))) void*)(As + (i2 * 512 + w * 64) * 8),
                16, 0, 0);
        }
#pragma unroll
        for (int i2 = 0; i2 < 4; ++i2) {
            int slot = i2 * 512 + tid;
            int r  = slot >> 3;
            int s  = slot & 7;
            int g  = s ^ (r & 7);
            const unsigned short* gb = xb + (size_t)(col0 + r) * D_ + k0 + g * 8;
            __builtin_amdgcn_global_load_lds(
                (const __attribute__((address_space(1))) void*)gb,
                (__attribute__((address_space(3))) void*)(Bs + (i2 * 512 + w * 64) * 8),
                16, 0, 0);
        }
        __syncthreads();   // barrier drains vmcnt -> LDS valid

#pragma unroll
        for (int kc = 0; kc < 2; ++kc) {
            bf16x8 aF[4], bF[4];
#pragma unroll
            for (int mi = 0; mi < 4; ++mi) {
                int rA = wrow * 64 + mi * 16 + l15;
                int g  = kc * 4 + q;
                int s  = g ^ (rA & 7);
                aF[mi] = *reinterpret_cast<const bf16x8*>(As + rA * 64 + s * 8);
            }
#pragma unroll
            for (int ni = 0; ni < 4; ++ni) {
                int rB = wcol * 64 + ni * 16 + l15;
                int g  = kc * 4 + q;
                int s  = g ^ (rB & 7);
                bF[ni] = *reinterpret_cast<const bf16x8*>(Bs + rB * 64 + s * 8);
            }
#pragma unroll
            for (int mi = 0; mi < 4; ++mi)
#pragma unroll
                for (int ni = 0; ni < 4; ++ni)
                    acc[mi][ni] = __builtin_amdgcn_mfma_f32_16x16x32_bf16(
                        aF[mi], bF[ni], acc[mi][ni], 0, 0, 0);
        }
    }

    // epilogue: single exp per element; row + col partials (dead waves -> zeros)
    float ps[4][4], ns[4][4];
    float cps[4], cns[4];
#pragma unroll
    for (int mi = 0; mi < 4; ++mi)
#pragma unroll
        for (int r = 0; r < 4; ++r) { ps[mi][r] = 0.f; ns[mi][r] = 0.f; }
#pragma unroll
    for (int ni = 0; ni < 4; ++ni) { cps[ni] = 0.f; cns[ni] = 0.f; }

    if (rowOK) {
#pragma unroll
        for (int mi = 0; mi < 4; ++mi)
#pragma unroll
            for (int ni = 0; ni < 4; ++ni)
#pragma unroll
                for (int r = 0; r < 4; ++r) {
                    float s = acc[mi][ni][r];
                    bool same = (tR[mi][r] == tC[ni]);
                    float e = __expf(same ? 1.0f - s : s);
                    float pe = (same && (s < 1.0f)) ? e : 0.0f;
                    float ne = same ? 0.0f : e;
                    ps[mi][r] += pe; ns[mi][r] += ne;
                    cps[ni]   += pe; cns[ni]   += ne;
                }
    }

    // combine through LDS (reuse As after barrier), then coalesced stores
    __syncthreads();
    float* scr = (float*)As;
    // [0:512)    rowP  [wcol][128]
    // [512:1024) rowN  [wcol][128]
    // [1024:1536) colP [wrow][256]
    // [1536:2048) colN [wrow][256]

#pragma unroll
    for (int mi = 0; mi < 4; ++mi)
#pragma unroll
        for (int r = 0; r < 4; ++r) {
            float p = ps[mi][r];
            float n = ns[mi][r];
#pragma unroll
            for (int m = 1; m < 16; m <<= 1) {
                p += __shfl_xor(p, m, 64);
                n += __shfl_xor(n, m, 64);
            }
            if (l15 == 0) {
                int rloc = wrow * 64 + mi * 16 + q * 4 + r;
                scr[wcol * 128 + rloc]       = p;
                scr[512 + wcol * 128 + rloc] = n;
            }
        }

#pragma unroll
    for (int ni = 0; ni < 4; ++ni) {
        float p = cps[ni];
        float n = cns[ni];
        p += __shfl_xor(p, 16, 64); p += __shfl_xor(p, 32, 64);
        n += __shfl_xor(n, 16, 64); n += __shfl_xor(n, 32, 64);
        if (q == 0) {
            int cloc = wcol * 64 + ni * 16 + l15;   // 0..255
            scr[1024 + wrow * 256 + cloc] = p;
            scr[1536 + wrow * 256 + cloc] = n;
        }
    }
    __syncthreads();

    if (tid < 128) {
        // row-sourced slot for tile it
        int r = tid;
        int s_row = it + jt2 - (it >> 1);
        size_t off = ((size_t)it * T_ + s_row) * 128 + r;
        bufP[off] = scr[r] + scr[128 + r] + scr[256 + r] + scr[384 + r];
        bufN[off] = scr[512 + r] + scr[640 + r] + scr[768 + r] + scr[896 + r];
    } else if (tid < 384) {
        // col-sourced slots: tile bc, slot it
        int c  = tid - 128;                 // 0..255
        int bc = 2 * jt2 + (c >> 7);
        if (bc > it) {
            size_t off = ((size_t)bc * T_ + it) * 128 + (c & 127);
            bufP[off] = scr[1024 + c] + scr[1280 + c];
            bufN[off] = scr[1536 + c] + scr[1792 + c];
        }
    }
}

// ---------- kernel 3: exact fp64 last-row dots -> sim_last[j] ----------
__global__ __launch_bounds__(256) void k_last(const float* __restrict__ x,
                                              double* __restrict__ sim_last) {
    int j    = (blockIdx.x * 256 + threadIdx.x) >> 6;
    int lane = threadIdx.x & 63;
    const float* xl = x + (size_t)(N_ - 1) * D_;
    const float* xj = x + (size_t)j * D_;
    double acc = 0.0;
#pragma unroll
    for (int it = 0; it < 8; ++it) {
        int k = it * 64 + lane;
        acc += (double)xl[k] * (double)xj[k];
    }
#pragma unroll
    for (int m = 32; m >= 1; m >>= 1) acc += __shfl_xor(acc, m, 64);
    if (lane == 0) sim_last[j] = acc;
}

// ---------- kernel 4: reduce packed partials -> psum/nsum ----------
// tile t: valid slots s in [0, t + 32 - (t>>1)), contiguous, each written once
__global__ __launch_bounds__(256) void k_reduce(const float* __restrict__ bufP,
                                                const float* __restrict__ bufN,
                                                float* __restrict__ psum,
                                                float* __restrict__ nsum) {
    int t    = blockIdx.x;            // 0..63
    int half = threadIdx.x >> 7;      // 0: psum, 1: nsum
    int r    = threadIdx.x & 127;
    int smax = t + 32 - (t >> 1);
    const float* buf = half ? bufN : bufP;
    const float* base = buf + (size_t)t * T_ * 128 + r;
    float s = 0.f;
    for (int o = 0; o < smax; ++o) s += base[o * 128];
    if (half) nsum[t * 128 + r] = s;
    else      psum[t * 128 + r] = s;
}

// ---------- kernel 5: finalize (single block, 1024 threads) ----------
__global__ __launch_bounds__(1024) void k_final(const float* __restrict__ psum,
                                                const float* __restrict__ nsum,
                                                const int* __restrict__ tg,
                                                const double* __restrict__ sim_last,
                                                float* __restrict__ out) {
    __shared__ int lh[NC_];
    __shared__ double sl[1024], sp[1024], sn[1024];
    __shared__ int    sk[1024], cp[1024], cn[1024];
    int tid = threadIdx.x;

    if (tid < NC_) lh[tid] = 0;
    __syncthreads();
    for (int i = tid; i < N_; i += 1024) atomicAdd(&lh[tg[i]], 1);
    __syncthreads();

    double part = 0.0;
    int skip = 0;
    for (int i = tid; i < N_; i += 1024) {
        if (lh[tg[i]] < N_) {
            part += (double)(logf(psum[i]) + logf(nsum[i]));
        } else {
            skip++;
        }
    }

    double pd = 0.0, nd = 0.0;
    int pc = 0, nc = 0;
    int tlast = tg[N_ - 1];
    for (int j = tid; j < N_; j += 1024) {
        double s = sim_last[j];
        if (tg[j] == tlast) {
            if (s < 1.0) { pd += s; pc++; }
        } else {
            nd += s; nc++;
        }
    }

    sl[tid] = part; sk[tid] = skip;
    sp[tid] = pd;   cp[tid] = pc;
    sn[tid] = nd;   cn[tid] = nc;
    __syncthreads();
    for (int s = 512; s >= 1; s >>= 1) {
        if (tid < s) {
            sl[tid] += sl[tid + s]; sk[tid] += sk[tid + s];
            sp[tid] += sp[tid + s]; cp[tid] += cp[tid + s];
            sn[tid] += sn[tid + s]; cn[tid] += cn[tid + s];
        }
        __syncthreads();
    }
    if (tid == 0) {
        out[0] = (float)(sl[0] / (double)N_);
        out[1] = (float)sk[0] / (float)N_;
        out[2] = (float)(sp[0] / (double)cp[0]);
        out[3] = (float)(sn[0] / (double)cn[0]);
    }
}

extern "C" void kernel_launch(void* const* d_in, const int* in_sizes, int n_in,
                              void* d_out, int out_size, void* d_ws, size_t ws_size,
                              hipStream_t stream) {
    const float* x  = (const float*)d_in[0];
    const int*   tg = (const int*)d_in[1];
    char* ws = (char*)d_ws;

    unsigned short* xb = (unsigned short*)ws;            // 8 MB
    const size_t XB = (size_t)N_ * D_ * 2;               // 8388608
    float*  psum     = (float*)(ws + XB);                // 32 KB
    float*  nsum     = (float*)(ws + XB + 32768);        // 32 KB
    double* sim_last = (double*)(ws + XB + 65536);       // 64 KB
    float*  bufP     = (float*)(ws + XB + 131072);       // 64*64*128*4 = 2 MB
    float*  bufN     = (float*)(ws + XB + 131072 + 2097152); // 2 MB

    // grid: sum over it of (32 - it/2) = 1056 blocks
    const int nblk = 1056;

    hipLaunchKernelGGL(k_convert, dim3((N_ * D_) / (256 * 4)), dim3(256), 0, stream, x, xb);
    hipLaunchKernelGGL(k_main, dim3(nblk), dim3(512), 0, stream, xb, tg, bufP, bufN);
    hipLaunchKernelGGL(k_last, dim3((N_ * 64) / 256), dim3(256), 0, stream, x, sim_last);
    hipLaunchKernelGGL(k_reduce, dim3(T_), dim3(256), 0, stream, bufP, bufN, psum, nsum);
    hipLaunchKernelGGL(k_final, dim3(1), dim3(1024), 0, stream,
                       psum, nsum, tg, sim_last, (float*)d_out);
}